// Round 6
// baseline (196.170 us; speedup 1.0000x reference)
//
#include <hip/hip_runtime.h>

#define S_NODES 512          // nodes per bucket (dst_local = dst & 511)
#define S_SHIFT 9
#define CAP     10240        // bucket capacity (mean ~8163, 25% slack)
#define CHUNK   8192         // edges per scatter block
#define FTH     512          // fused kernel block size
#define NDOTS   192          // dots-role blocks in fused kernel

// Fused: scatter-bucket (blocks [0,nscat)) + weight-fold/dots (blocks [nscat, nscat+NDOTS)).
// Packed edge: (src << 9) | (dst & 511)  (src < 2^17 -> 26 bits).
__global__ __launch_bounds__(512) void fused_kernel(
    const float* __restrict__ x,
    const int* __restrict__ src, const int* __restrict__ dst, int E, int B, int nscat,
    int* __restrict__ cursor, unsigned* __restrict__ bucket,
    const float* __restrict__ Wl1, const float* __restrict__ Wr1, const float* __restrict__ b1,
    const float* __restrict__ Wl2, const float* __restrict__ Wr2, const float* __restrict__ b2,
    const float* __restrict__ Wfc1, const float* __restrict__ bfc1,
    const float* __restrict__ Wfc2, const float* __restrict__ bfc2,
    float* __restrict__ ga, float2* __restrict__ gbc, float* __restrict__ c01, int N)
{
    // scatter-role LDS
    __shared__ unsigned pk[CHUNK];
    __shared__ unsigned char bn[CHUNK];
    __shared__ int hist[256], lbase[256], lcur[256];
    // dots-role LDS
    __shared__ float u[128], vl2[128], vr2[128], w2[32], wv[192];

    int t = threadIdx.x;
    if ((int)blockIdx.x < nscat) {
        // ---------- scatter role: bucket edges with block-local write combining ----------
        int e0 = blockIdx.x * CHUNK;
        int cnt = E - e0; if (cnt > CHUNK) cnt = CHUNK;
        if (t < 256) { hist[t] = 0; lcur[t] = 0; }
        __syncthreads();
        for (int i = t; i < cnt; i += FTH) {
            int s = src[e0 + i], d = dst[e0 + i];
            int b = d >> S_SHIFT;
            pk[i] = ((unsigned)s << S_SHIFT) | (unsigned)(d & (S_NODES - 1));
            bn[i] = (unsigned char)b;
            atomicAdd(&hist[b], 1);
        }
        __syncthreads();
        if (t < B && hist[t] > 0) lbase[t] = atomicAdd(&cursor[t], hist[t]);
        __syncthreads();
        for (int i = t; i < cnt; i += FTH) {
            int b = bn[i];
            int off = atomicAdd(&lcur[b], 1);
            bucket[(size_t)b * CAP + (unsigned)(lbase[b] + off)] = pk[i];
        }
    } else {
        // ---------- dots role: redundant weight fold in LDS, then per-node dots ----------
        if (t < 32) w2[t] = Wfc2[t];
        __syncthreads();
        if (t < 128) {   // u = Wfc1 @ Wfc2
            float s = 0.f;
            for (int k = 0; k < 32; ++k) s += Wfc1[t * 32 + k] * w2[k];
            u[t] = s;
        }
        __syncthreads();
        if (t < 128) {   // vl2 = Wl2 @ u, vr2 = Wr2 @ u
            float a = 0.f, b = 0.f;
            for (int k = 0; k < 128; ++k) {
                a += Wl2[t * 128 + k] * u[k];
                b += Wr2[t * 128 + k] * u[k];
            }
            vl2[t] = a; vr2[t] = b;
        }
        __syncthreads();
        if (t < 64) {    // w_a, w_b, w_c
            float wa = 0.f, wb = 0.f, wc = 0.f;
            for (int j = 0; j < 128; ++j) {
                float l1 = Wl1[t * 128 + j], r1 = Wr1[t * 128 + j];
                wc += l1 * vl2[j];
                wb += l1 * vr2[j] + r1 * vl2[j];
                wa += r1 * vr2[j];
            }
            wv[t] = wa; wv[64 + t] = wb; wv[128 + t] = wc;
        }
        if ((int)blockIdx.x == nscat && t == 0) {   // one block publishes c0,c1
            float c0 = bfc2[0], c1 = 0.f;
            for (int j = 0; j < 128; ++j) {
                c0 += b1[j] * vr2[j] + b2[j] * u[j];
                c1 += b1[j] * vl2[j];
            }
            for (int k = 0; k < 32; ++k) c0 += bfc1[k] * w2[k];
            c01[0] = c0; c01[1] = c1;
        }
        __syncthreads();
        int lane = t & 63, sub = t >> 6;   // 8 nodes per iteration (one per wave)
        float wa = wv[lane], wb = wv[64 + lane], wc = wv[128 + lane];
        int ngroups = (N + 7) / 8;
        for (int g = (int)blockIdx.x - nscat; g < ngroups; g += NDOTS) {
            int node = g * 8 + sub;
            if (node >= N) continue;
            float v = x[(size_t)node * 64 + lane];
            float a = v * wa, b = v * wb, c = v * wc;
            for (int off = 32; off > 0; off >>= 1) {
                a += __shfl_down(a, off);
                b += __shfl_down(b, off);
                c += __shfl_down(c, off);
            }
            if (lane == 0) { ga[node] = a; gbc[node] = make_float2(b, c); }
        }
    }
}

// One block per bucket, 1024 threads (16 waves for latency hiding).
__global__ __launch_bounds__(1024) void aggA_kernel(
    const unsigned* __restrict__ bucket, const int* __restrict__ cursor,
    const float2* __restrict__ gbc, const float* __restrict__ ga,
    const float* __restrict__ c01,
    float* __restrict__ q, float* __restrict__ t1, float* __restrict__ inv, int N)
{
    __shared__ float aB[S_NODES], aC[S_NODES];
    __shared__ int cnt[S_NODES];
    int t = threadIdx.x, b = blockIdx.x;
    if (t < S_NODES) { aB[t] = 0.f; aC[t] = 0.f; cnt[t] = 0; }
    __syncthreads();
    int n = cursor[b];
    const unsigned* bp = bucket + (size_t)b * CAP;
    for (int i = t; i < n; i += 1024) {
        unsigned uu = bp[i];
        float2 g = gbc[uu >> S_SHIFT];   // 8B gather, 800KB L2-resident table
        int dl = uu & (S_NODES - 1);
        atomicAdd(&aB[dl], g.x);
        atomicAdd(&aC[dl], g.y);
        atomicAdd(&cnt[dl], 1);
    }
    __syncthreads();
    if (t < S_NODES) {
        int node = (b << S_SHIFT) + t;
        if (node < N) {
            int d = cnt[t];
            float iv = 1.0f / ((d > 0) ? (float)d : 1.0f);
            inv[node] = iv;
            q[node]   = iv * aC[t];
            t1[node]  = ga[node] + iv * aB[t] + c01[0] + (d > 0 ? c01[1] : 0.f);
        }
    }
}

__global__ __launch_bounds__(1024) void aggB_kernel(
    const unsigned* __restrict__ bucket, const int* __restrict__ cursor,
    const float* __restrict__ q, const float* __restrict__ t1,
    const float* __restrict__ inv, float* __restrict__ out, int N)
{
    __shared__ float a2[S_NODES];
    int t = threadIdx.x, b = blockIdx.x;
    if (t < S_NODES) a2[t] = 0.f;
    __syncthreads();
    int n = cursor[b];
    const unsigned* bp = bucket + (size_t)b * CAP;
    for (int i = t; i < n; i += 1024) {
        unsigned uu = bp[i];
        atomicAdd(&a2[uu & (S_NODES - 1)], q[uu >> S_SHIFT]);
    }
    __syncthreads();
    if (t < S_NODES) {
        int node = (b << S_SHIFT) + t;
        if (node < N) out[node] = t1[node] + inv[node] * a2[t];
    }
}

extern "C" void kernel_launch(void* const* d_in, const int* in_sizes, int n_in,
                              void* d_out, int out_size, void* d_ws, size_t ws_size,
                              hipStream_t stream) {
    const float* x    = (const float*)d_in[0];
    const int*   eidx = (const int*)d_in[1];   // [2, E]
    // d_in[2] = edge_weight: unused by the reference
    const float* Wl1  = (const float*)d_in[3];
    const float* Wr1  = (const float*)d_in[4];
    const float* b1   = (const float*)d_in[5];
    const float* Wl2  = (const float*)d_in[6];
    const float* Wr2  = (const float*)d_in[7];
    const float* b2   = (const float*)d_in[8];
    const float* Wfc1 = (const float*)d_in[9];
    const float* bfc1 = (const float*)d_in[10];
    const float* Wfc2 = (const float*)d_in[11];
    const float* bfc2 = (const float*)d_in[12];

    const int N = in_sizes[0] / 64;
    const int E = in_sizes[2];
    const int* src = eidx;
    const int* dst = eidx + E;
    const int B = (N + S_NODES - 1) / S_NODES;       // 196 buckets (<= 256)
    const int nscat = (E + CHUNK - 1) / CHUNK;       // 196 scatter blocks

    // workspace: [cursor 1KB][c01 1KB][ga 4N][q 4N][t1 4N][inv 4N][gbc 8N][bucket B*CAP*4]
    char* ws = (char*)d_ws;
    int*      cursor = (int*)(ws);
    float*    c01    = (float*)(ws + 1024);
    float*    ga     = (float*)(ws + 2048);
    float*    q      = (float*)(ws + 2048 + (size_t)N * 4);
    float*    t1     = (float*)(ws + 2048 + (size_t)N * 8);
    float*    inv    = (float*)(ws + 2048 + (size_t)N * 12);
    float2*   gbc    = (float2*)(ws + 2048 + (size_t)N * 16);
    unsigned* bucket = (unsigned*)(ws + 2048 + (size_t)N * 24);

    hipMemsetAsync(cursor, 0, 1024, stream);

    fused_kernel<<<nscat + NDOTS, FTH, 0, stream>>>(
        x, src, dst, E, B, nscat, cursor, bucket,
        Wl1, Wr1, b1, Wl2, Wr2, b2, Wfc1, bfc1, Wfc2, bfc2,
        ga, gbc, c01, N);

    aggA_kernel<<<B, 1024, 0, stream>>>(bucket, cursor, gbc, ga, c01, q, t1, inv, N);
    aggB_kernel<<<B, 1024, 0, stream>>>(bucket, cursor, q, t1, inv, (float*)d_out, N);
}